// Round 1
// baseline (258.250 us; speedup 1.0000x reference)
//
#include <hip/hip_runtime.h>
#include <math.h>

#define NN 50000
#define NE 800000
// IN=256, MAP=64, H=4, O=64
#define LEAKY 0.2f
#define NT 26              // 26 column tiles of 16 (416 cols, 400 real)
#define CAP 96             // padded CSR slots/node (max deg over Poisson(16) << 96)
#define NBT (8 * NT * 64)  // Btf fragment count
#define NRB 3125           // row blocks of 16 (NN/16 exact)
#define PACK_BLKS 6250     // NRB*512/256
#define BT_BLKS 54         // ceil((NBT+512)/256)
#define INIT_BLKS 196      // ceil(NN/256)

typedef short bf16x8 __attribute__((ext_vector_type(8)));
typedef float f32x4 __attribute__((ext_vector_type(4)));
typedef float f32x2 __attribute__((ext_vector_type(2)));

__device__ __forceinline__ unsigned short f2bf(float f) {
  unsigned u = __float_as_uint(f);
  u += 0x7fffu + ((u >> 16) & 1u);
  return (unsigned short)(u >> 16);
}
__device__ __forceinline__ float leaky(float v) { return v > 0.0f ? v : LEAKY * v; }
__device__ __forceinline__ float rlf(float v, int l) {
  return __uint_as_float(__builtin_amdgcn_readlane(__float_as_uint(v), l));
}
__device__ __forceinline__ int rli(int v, int l) {
  return __builtin_amdgcn_readlane(v, l);
}

// ---- fp8 e4m3fn helpers (HW cvt on gfx950; software fallback) ----
#if defined(__has_builtin)
#if __has_builtin(__builtin_amdgcn_cvt_pk_f32_fp8) && \
    __has_builtin(__builtin_amdgcn_cvt_pk_fp8_f32) && \
    __has_builtin(__builtin_amdgcn_cvt_f32_fp8)
#define FP8_HW 1
#endif
#endif

#ifdef FP8_HW
__device__ __forceinline__ unsigned char f2fp8(float v) {
  return (unsigned char)(__builtin_amdgcn_cvt_pk_fp8_f32(v, v, 0u, false) & 0xFF);
}
__device__ __forceinline__ f32x2 fp8x2_lo(unsigned int v) {
  return __builtin_amdgcn_cvt_pk_f32_fp8(v, false);   // word-select must be literal
}
__device__ __forceinline__ f32x2 fp8x2_hi(unsigned int v) {
  return __builtin_amdgcn_cvt_pk_f32_fp8(v, true);
}
__device__ __forceinline__ float fp8one(unsigned int v) {
  return __builtin_amdgcn_cvt_f32_fp8(v, 0);
}
#else
__device__ __forceinline__ unsigned char f2fp8(float f) {
  unsigned u = __float_as_uint(f);
  unsigned s = (u >> 31) << 7;
  unsigned a = u & 0x7FFFFFFFu;
  if (a >= 0x43E00000u) return (unsigned char)(s | 0x7E);
  if (a < 0x3C800000u) {
    float m = __uint_as_float(a) * 512.0f;
    int q = (int)(m + 0.5f); if (q > 7) q = 7;
    return (unsigned char)(s | q);
  }
  a += 0x7FFFFu + ((a >> 20) & 1);
  unsigned e = ((a >> 23) & 0xFF) - 120;
  if (e > 15) return (unsigned char)(s | 0x7E);
  return (unsigned char)(s | (e << 3) | ((a >> 20) & 7));
}
__device__ __forceinline__ float fp8dec1(unsigned b) {
  unsigned s = (b & 0x80u) << 24;
  unsigned em = b & 0x7Fu;
  unsigned e4 = em >> 3, m3 = em & 7;
  float v = e4 ? __uint_as_float(((e4 + 120) << 23) | (m3 << 20))
               : (float)m3 * 0.001953125f;
  return __uint_as_float(__float_as_uint(v) ^ s);
}
__device__ __forceinline__ f32x2 fp8x2_lo(unsigned int v) {
  f32x2 r; r[0] = fp8dec1(v & 0xFF); r[1] = fp8dec1((v >> 8) & 0xFF); return r;
}
__device__ __forceinline__ f32x2 fp8x2_hi(unsigned int v) {
  f32x2 r; r[0] = fp8dec1((v >> 16) & 0xFF); r[1] = fp8dec1((v >> 24) & 0xFF); return r;
}
__device__ __forceinline__ float fp8one(unsigned int v) { return fp8dec1(v & 0xFF); }
#endif

// Panel columns (416 = 26 tiles of 16):
//  c in 0..255   : feat, PERMUTED: panel col c holds W_gat column (c&3)*64 + (c>>2)
//                  so the GEMM output is featq[row][o*4+h] (o=c>>2, h=c&3)
//  c in 256..319 : gate_m_W (z)
//  c in 320..383 : merge_W[0:256] (xm)
//  c in 384..387 : gate_fn_W x-part (gx)
//  c in 388..391 : gate_fn_W mean-part (u)
//  c >= 392      : zero pad
__device__ __forceinline__ float panel_w(int col, int k,
    const float* W_gat, const float* gate_m_W, const float* merge_W,
    const float* gate_fn_W) {
  if (col < 256)      return W_gat[k * 256 + (col & 3) * 64 + (col >> 2)];
  else if (col < 320) return gate_m_W[k * 64 + (col - 256)];
  else if (col < 384) return merge_W[k * 64 + (col - 320)];
  else if (col < 388) return gate_fn_W[k * 4 + (col - 384)];
  else if (col < 392) return gate_fn_W[(320 + k) * 4 + (col - 388)];
  return 0.0f;
}

// Fused prep: x->xf (bf16 A-fragments) | Btf+mWf weight fragments | cursor zero + sentinels
__global__ __launch_bounds__(256) void k_prep(
    const float* __restrict__ x, const float* __restrict__ W_gat,
    const float* __restrict__ gate_m_W, const float* __restrict__ merge_W,
    const float* __restrict__ gate_fn_W,
    unsigned short* __restrict__ xf, unsigned short* __restrict__ Btf,
    unsigned short* __restrict__ mWf,
    int* __restrict__ cursor, unsigned char* __restrict__ zq,
    float* __restrict__ epay, unsigned char* __restrict__ featq) {
  int b = blockIdx.x, tid = threadIdx.x;
  if (b < PACK_BLKS) {
    // xf[((rowblk*8 + kq)*64 + lane)*8 + i] = bf16(x[rowblk*16 + (lane&15)][kq*32+(lane>>4)*8+i])
    int gid = b * 256 + tid;
    int rowblk = gid >> 9;
    int rem = gid & 511;
    int kq = rem >> 6, lane = rem & 63;
    int m = lane & 15, kg = lane >> 4;
    const float* p = x + (size_t)(rowblk * 16 + m) * 256 + kq * 32 + kg * 8;
    float4 fa = *(const float4*)p;
    float4 fb = *(const float4*)(p + 4);
    ushort4 o0, o1;
    o0.x = f2bf(fa.x); o0.y = f2bf(fa.y); o0.z = f2bf(fa.z); o0.w = f2bf(fa.w);
    o1.x = f2bf(fb.x); o1.y = f2bf(fb.y); o1.z = f2bf(fb.z); o1.w = f2bf(fb.w);
    ushort4* dst = (ushort4*)(xf + (size_t)gid * 8);
    dst[0] = o0; dst[1] = o1;
  } else if (b < PACK_BLKS + BT_BLKS) {
    int idx = (b - PACK_BLKS) * 256 + tid;
    if (idx < NBT) {
      int kq = idx / (NT * 64);
      int rem = idx - kq * (NT * 64);
      int t = rem >> 6, lane = rem & 63;
      int col = t * 16 + (lane & 15);
      int k = kq * 32 + (lane >> 4) * 8;
      unsigned short* o = Btf + (size_t)idx * 8;
#pragma unroll
      for (int i = 0; i < 8; ++i)
        o[i] = f2bf(panel_w(col, k + i, W_gat, gate_m_W, merge_W, gate_fn_W));
    } else if (idx < NBT + 512) {
      int idx2 = idx - NBT;
      int kq = idx2 >> 8;
      int rem = idx2 & 255;
      int t = rem >> 6, lane = rem & 63;
      int col = t * 16 + (lane & 15);
      int k = kq * 32 + ((lane >> 4) & 3) * 8;
      unsigned short* o = mWf + (size_t)idx2 * 8;
#pragma unroll
      for (int i = 0; i < 8; ++i)
        o[i] = f2bf(merge_W[(size_t)(256 + k + i) * 64 + col]);
    }
  } else {
    int i = (b - PACK_BLKS - BT_BLKS) * 256 + tid;
    if (i < NN) cursor[i] = 0;
    if (b == PACK_BLKS + BT_BLKS) {
      if (tid < 64) zq[(size_t)NN * 64 + tid] = 0xFE;   // sentinel z = -448
      if (tid < 8) epay[(size_t)NN * 8 + tid] = 0.0f;   // sentinel el/u = 0
      featq[(size_t)NN * 256 + tid] = 0;                // sentinel feat = 0 (no fp8 NaN)
    }
  }
}

// Padded CSR scatter (uint16 src ids: NN < 65536)
__global__ void k_scatter(const int* __restrict__ src, const int* __restrict__ dst,
                          int* __restrict__ cursor, unsigned short* __restrict__ csr_src) {
  int e = blockIdx.x * 256 + threadIdx.x;
  if (e < NE) {
    int n = dst[e];
    int pos = atomicAdd(&cursor[n], 1);
    if (pos < CAP) csr_src[n * CAP + pos] = (unsigned short)src[e];
  }
}

// bf16 MFMA GEMM: block = 64 rows x 416 cols, 4 waves; wave (rowHalf, colHalf) does
// TWO 16-row groups x 13 tiles (B loaded once per 32 rows -> half the B refetch).
// Ping-pong double-buffer on A and B fragments (vmcnt never drains the prefetch).
__global__ __launch_bounds__(256, 2) void k_gemm_mfma(
    const unsigned short* __restrict__ xf, const unsigned short* __restrict__ Btf,
    const float* __restrict__ gate_m_b,
    const float* __restrict__ attn_l, const float* __restrict__ attn_r,
    unsigned char* __restrict__ featq, unsigned char* __restrict__ zq,
    float* __restrict__ xm, float* __restrict__ gx, float* __restrict__ epay,
    float* __restrict__ erv) {
  __shared__ float els[64][4][2];
  __shared__ float ers[64][4][2];
  int lane = threadIdx.x & 63;
  int wave = threadIdx.x >> 6;
  int rowHalf = wave >> 1, colHalf = wave & 1;
  int rowB = blockIdx.x * 64;
  int row0 = rowB + rowHalf * 32;
  int t0 = colHalf * 13;
  int m = lane & 15, kg = lane >> 4;
  f32x4 zero = {0.f, 0.f, 0.f, 0.f};
  f32x4 acc[2][13];
#pragma unroll
  for (int g = 0; g < 2; ++g)
#pragma unroll
    for (int t = 0; t < 13; ++t) acc[g][t] = zero;

  const unsigned short* aB0 = xf + ((size_t)((blockIdx.x * 4 + rowHalf * 2) * 8) * 64 + lane) * 8;
  const unsigned short* aB1 = aB0 + (size_t)8 * 64 * 8;   // next 16-row block
  const unsigned short* bB = Btf + (size_t)(t0 * 64 + lane) * 8;

  bf16x8 aC0, aC1, aN0, aN1, bC[13], bN[13];
  aC0 = *(const bf16x8*)(aB0);
  aC1 = *(const bf16x8*)(aB1);
#pragma unroll
  for (int t = 0; t < 13; ++t)
    bC[t] = *(const bf16x8*)(bB + (size_t)t * 512);
#pragma unroll 1
  for (int kq = 0; kq < 8; kq += 2) {
    aN0 = *(const bf16x8*)(aB0 + (size_t)(kq + 1) * 512);
    aN1 = *(const bf16x8*)(aB1 + (size_t)(kq + 1) * 512);
#pragma unroll
    for (int t = 0; t < 13; ++t)
      bN[t] = *(const bf16x8*)(bB + ((size_t)(kq + 1) * NT + t) * 512);
#pragma unroll
    for (int t = 0; t < 13; ++t)
      acc[0][t] = __builtin_amdgcn_mfma_f32_16x16x32_bf16(aC0, bC[t], acc[0][t], 0, 0, 0);
#pragma unroll
    for (int t = 0; t < 13; ++t)
      acc[1][t] = __builtin_amdgcn_mfma_f32_16x16x32_bf16(aC1, bC[t], acc[1][t], 0, 0, 0);
    int kq2 = kq + 2 < 8 ? kq + 2 : 7;
    aC0 = *(const bf16x8*)(aB0 + (size_t)kq2 * 512);
    aC1 = *(const bf16x8*)(aB1 + (size_t)kq2 * 512);
#pragma unroll
    for (int t = 0; t < 13; ++t)
      bC[t] = *(const bf16x8*)(bB + ((size_t)kq2 * NT + t) * 512);
#pragma unroll
    for (int t = 0; t < 13; ++t)
      acc[0][t] = __builtin_amdgcn_mfma_f32_16x16x32_bf16(aN0, bN[t], acc[0][t], 0, 0, 0);
#pragma unroll
    for (int t = 0; t < 13; ++t)
      acc[1][t] = __builtin_amdgcn_mfma_f32_16x16x32_bf16(aN1, bN[t], acc[1][t], 0, 0, 0);
  }

  // fused el/er partials: h = m&3, o = (t0+t)*4 + (m>>2), feat tiles only
  int h = m & 3, od = m >> 2;
  float elp[2][4] = {{0,0,0,0},{0,0,0,0}}, erp[2][4] = {{0,0,0,0},{0,0,0,0}};
#pragma unroll
  for (int t = 0; t < 13; ++t) {
    if ((t0 + t) * 16 < 256) {
      int o = (t0 + t) * 4 + od;
      float al = attn_l[h * 64 + o];
      float ar = attn_r[h * 64 + o];
#pragma unroll
      for (int g = 0; g < 2; ++g)
#pragma unroll
        for (int r = 0; r < 4; ++r) {
          elp[g][r] += acc[g][t][r] * al;
          erp[g][r] += acc[g][t][r] * ar;
        }
    }
  }
#pragma unroll
  for (int g = 0; g < 2; ++g)
#pragma unroll
    for (int r = 0; r < 4; ++r) {
      elp[g][r] += __shfl_xor(elp[g][r], 4, 64); elp[g][r] += __shfl_xor(elp[g][r], 8, 64);
      erp[g][r] += __shfl_xor(erp[g][r], 4, 64); erp[g][r] += __shfl_xor(erp[g][r], 8, 64);
    }
  if (m < 4) {
#pragma unroll
    for (int g = 0; g < 2; ++g)
#pragma unroll
      for (int r = 0; r < 4; ++r) {
        els[rowHalf * 32 + g * 16 + kg * 4 + r][m][colHalf] = elp[g][r];
        ers[rowHalf * 32 + g * 16 + kg * 4 + r][m][colHalf] = erp[g][r];
      }
  }

  // epilogue stores: wave-uniform colHalf branch
#pragma unroll
  for (int g = 0; g < 2; ++g) {
    if (colHalf == 0) {
#pragma unroll
      for (int r = 0; r < 4; ++r) {
        int row = row0 + g * 16 + kg * 4 + r;
        if (row >= NN) continue;
#pragma unroll
        for (int t = 0; t < 13; ++t)
          featq[(size_t)row * 256 + t * 16 + m] = f2fp8(acc[g][t][r]);
      }
    } else {
#pragma unroll
      for (int r = 0; r < 4; ++r) {
        int row = row0 + g * 16 + kg * 4 + r;
        if (row >= NN) continue;
#pragma unroll
        for (int t = 0; t < 3; ++t)          // tiles 13..15: feat cols 208+
          featq[(size_t)row * 256 + 208 + t * 16 + m] = f2fp8(acc[g][t][r]);
#pragma unroll
        for (int t = 3; t < 7; ++t) {        // tiles 16..19: z
          int cc = (t - 3) * 16 + m;
          zq[(size_t)row * 64 + cc] = f2fp8(acc[g][t][r] + gate_m_b[cc]);
        }
#pragma unroll
        for (int t = 7; t < 11; ++t)         // tiles 20..23: xm
          xm[(size_t)row * 64 + (t - 7) * 16 + m] = acc[g][t][r];
        if (m < 4) gx[(size_t)row * 4 + m] = acc[g][11][r];                   // gx
        else if (m < 8) epay[(size_t)row * 8 + (m - 4) * 2 + 1] = acc[g][11][r];  // u
      }
    }
  }
  __syncthreads();
  int tid = threadIdx.x;
  {
    int rr = tid >> 2, h2 = tid & 3;
    int row = rowB + rr;
    if (row < NN) {
      epay[(size_t)row * 8 + h2 * 2] = els[rr][h2][0] + els[rr][h2][1];
      erv[(size_t)row * 4 + h2] = ers[rr][h2][0] + ers[rr][h2][1];
    }
  }
}

// Block = 16 nodes (4 per wave, sequential), single pass per node, 16-edge chunks.
// QUARTER-SPLIT gather: each 16-lane quarter owns one edge per inner step, loading
// the full 256B featq row as dwordx4 (16B/lane) and 4B of zq -> 4 edges per
// load instruction (was 1), addresses/readlane/ds_read amortized 4x.  Decode and
// accumulate in f32x2 (packed v_pk_fma_f32).  Lane lq owns output cols
// 16*lq..16*lq+15 (o = 4*lq..4*lq+3, all 4 heads); cross-quarter shfl reduce once
// per node.  p broadcast via LDS as before; merge GEMM fused at block end via MFMA.
__global__ __launch_bounds__(256) void k_node(
    const unsigned char* __restrict__ zq, const unsigned char* __restrict__ featq,
    const float* __restrict__ epay, const float* __restrict__ er,
    const float* __restrict__ gx,
    const int* __restrict__ cursor, const unsigned short* __restrict__ csr_src,
    const float* __restrict__ gate_fn_W, const float* __restrict__ gate_fn_b,
    const unsigned short* __restrict__ mWf, const float* __restrict__ xm,
    const float* __restrict__ merge_b, float* __restrict__ out) {
  __shared__ float WzT[4][64];             // gate_fn_W max_z-part, transposed [h][c]
  __shared__ float pbuf[4][16][4];         // [wave][edge][head]
  __shared__ unsigned short gLDS[16][72];  // gated bf16, padded stride
  int tid = threadIdx.x;
  {
    int c = tid >> 2, h = tid & 3;
    WzT[h][c] = gate_fn_W[(256 + c) * 4 + h];
  }
  __syncthreads();

  int lane = tid & 63, wave = tid >> 6;
  int hh = lane >> 4;      // head for p computation == quarter index
  int lq = lane & 15;      // edge slot for p computation == lane-in-quarter
  int nodeBase = blockIdx.x * 16 + wave * 4;
#pragma unroll 1
  for (int i = 0; i < 4; ++i) {
    int node = nodeBase + i;                    // 3125*16 == NN exactly
    int deg = cursor[node]; if (deg > CAP) deg = CAP;
    float go0 = 0.f, go1 = 0.f, go2 = 0.f, go3 = 0.f;
    if (deg > 0) {
      int rs = node * CAP, re = rs + deg;
      float er_h = er[(size_t)node * 4 + hh];
      f32x2 A[8];                               // cols 16*lq + 2j .. +2j+1
#pragma unroll
      for (int j = 0; j < 8; ++j) A[j] = (f32x2){0.f, 0.f};
      f32x2 M0 = {-INFINITY, -INFINITY};        // z cols 4*lq+{0,1}
      f32x2 M1 = {-INFINITY, -INFINITY};        // z cols 4*lq+{2,3}
      float psum = 0.f, usum = 0.f;
      for (int j0 = rs; j0 < re; j0 += 16) {
        int jj = j0 + lq;
        bool valid = jj < re;
        int s_l = valid ? (int)csr_src[jj] : NN;     // NN = sentinel row
        float2 eu = *(const float2*)(epay + ((size_t)(unsigned)s_l << 3) + hh * 2);
        float p = valid ? __expf(leaky(eu.x + er_h)) : 0.0f;
        psum += p;
        usum += eu.y;                                // sentinel u == 0
        pbuf[wave][lq][hh] = p;                      // wave-synchronous broadcast
#pragma unroll
        for (int it = 0; it < 4; ++it) {
          int es = it * 4 + hh;                      // this quarter's edge slot
          int s = __shfl(s_l, es, 64);               // ds_bpermute
          float4 pv = *(const float4*)pbuf[wave][es];  // p[edge][4 heads], qtr-uniform
          uint4 fv = *(const uint4*)(featq + ((size_t)(unsigned)s << 8) + lq * 16);
          unsigned int zv = *(const unsigned int*)(zq + ((size_t)(unsigned)s << 6) + lq * 4);
          f32x2 p01 = {pv.x, pv.y};                  // heads {0,1} (col&3 pattern)
          f32x2 p23 = {pv.z, pv.w};                  // heads {2,3}
          A[0] += p01 * fp8x2_lo(fv.x);
          A[1] += p23 * fp8x2_hi(fv.x);
          A[2] += p01 * fp8x2_lo(fv.y);
          A[3] += p23 * fp8x2_hi(fv.y);
          A[4] += p01 * fp8x2_lo(fv.z);
          A[5] += p23 * fp8x2_hi(fv.z);
          A[6] += p01 * fp8x2_lo(fv.w);
          A[7] += p23 * fp8x2_hi(fv.w);
          f32x2 zlo = fp8x2_lo(zv), zhi = fp8x2_hi(zv);
          M0[0] = fmaxf(M0[0], zlo[0]); M0[1] = fmaxf(M0[1], zlo[1]);
          M1[0] = fmaxf(M1[0], zhi[0]); M1[1] = fmaxf(M1[1], zhi[1]);
        }
      }
      // per-head p/u sums within each 16-lane group
#pragma unroll
      for (int off = 1; off < 16; off <<= 1) {
        psum += __shfl_xor(psum, off, 64);
        usum += __shfl_xor(usum, off, 64);
      }
      float s0 = rlf(psum, 0),  s1 = rlf(psum, 16);
      float s2 = rlf(psum, 32), s3 = rlf(psum, 48);
      float su0 = rlf(usum, 0),  su1 = rlf(usum, 16);
      float su2 = rlf(usum, 32), su3 = rlf(usum, 48);
      // cross-quarter reduce of A (sum) and M (max)
#pragma unroll
      for (int j = 0; j < 8; ++j) {
        A[j][0] += __shfl_xor(A[j][0], 16, 64); A[j][1] += __shfl_xor(A[j][1], 16, 64);
        A[j][0] += __shfl_xor(A[j][0], 32, 64); A[j][1] += __shfl_xor(A[j][1], 32, 64);
      }
      M0[0] = fmaxf(M0[0], __shfl_xor(M0[0], 16, 64));
      M0[1] = fmaxf(M0[1], __shfl_xor(M0[1], 16, 64));
      M1[0] = fmaxf(M1[0], __shfl_xor(M1[0], 16, 64));
      M1[1] = fmaxf(M1[1], __shfl_xor(M1[1], 16, 64));
      M0[0] = fmaxf(M0[0], __shfl_xor(M0[0], 32, 64));
      M0[1] = fmaxf(M0[1], __shfl_xor(M0[1], 32, 64));
      M1[0] = fmaxf(M1[0], __shfl_xor(M1[0], 32, 64));
      M1[1] = fmaxf(M1[1], __shfl_xor(M1[1], 32, 64));
      // gate: sigmoid(gx + Wz·max_z + mean-part + b); this lane holds z cols 4lq..+3
      float gq[4];
#pragma unroll
      for (int h = 0; h < 4; ++h) {
        float4 wz = *(const float4*)&WzT[h][lq * 4];
        float t = M0[0] * wz.x + M0[1] * wz.y + M1[0] * wz.z + M1[1] * wz.w;
#pragma unroll
        for (int off = 1; off < 16; off <<= 1) t += __shfl_xor(t, off, 64);
        gq[h] = t;
      }
      float inv_deg = 1.0f / (float)deg;
      float4 gx4 = *(const float4*)(gx + (size_t)node * 4);
      float g0 = 1.0f / (1.0f + __expf(-(gq[0] + gx4.x + su0 * inv_deg + gate_fn_b[0])));
      float g1 = 1.0f / (1.0f + __expf(-(gq[1] + gx4.y + su1 * inv_deg + gate_fn_b[1])));
      float g2 = 1.0f / (1.0f + __expf(-(gq[2] + gx4.z + su2 * inv_deg + gate_fn_b[2])));
      float g3 = 1.0f / (1.0f + __expf(-(gq[3] + gx4.w + su3 * inv_deg + gate_fn_b[3])));
      float r0 = 0.25f * g0 / s0, r1 = 0.25f * g1 / s1;
      float r2 = 0.25f * g2 / s2, r3 = 0.25f * g3 / s3;
      // gated for o = 4*lq + oo: col element oo*4+h -> A[2*oo + (h>>1)][h&1]
      go0 = r0 * A[0][0] + r1 * A[0][1] + r2 * A[1][0] + r3 * A[1][1];
      go1 = r0 * A[2][0] + r1 * A[2][1] + r2 * A[3][0] + r3 * A[3][1];
      go2 = r0 * A[4][0] + r1 * A[4][1] + r2 * A[5][0] + r3 * A[5][1];
      go3 = r0 * A[6][0] + r1 * A[6][1] + r2 * A[7][0] + r3 * A[7][1];
    }
    if (hh == 0) {
      ushort4 gw;
      gw.x = f2bf(go0); gw.y = f2bf(go1); gw.z = f2bf(go2); gw.w = f2bf(go3);
      *(ushort4*)&gLDS[wave * 4 + i][lq * 4] = gw;
    }
  }
  __syncthreads();

  // fused merge: out[16 rows][64] = gated @ merge_W[256:320] + xm + merge_b
  // wave w computes column tile w (cols w*16..+15); A shared from gLDS.
  int m = lane & 15, kg = lane >> 4;
  f32x4 acc = {0.f, 0.f, 0.f, 0.f};
#pragma unroll
  for (int kq = 0; kq < 2; ++kq) {
    bf16x8 a = *(const bf16x8*)(&gLDS[m][kq * 32 + kg * 8]);
    bf16x8 b = *(const bf16x8*)(mWf + (((size_t)kq * 4 + wave) * 64 + lane) * 8);
    acc = __builtin_amdgcn_mfma_f32_16x16x32_bf16(a, b, acc, 0, 0, 0);
  }
  int c = wave * 16 + m;
  float mb = merge_b[c];
#pragma unroll
  for (int r = 0; r < 4; ++r) {
    int row = blockIdx.x * 16 + kg * 4 + r;
    out[(size_t)row * 64 + c] = acc[r] + xm[(size_t)row * 64 + c] + mb;
  }
}

extern "C" void kernel_launch(void* const* d_in, const int* in_sizes, int n_in,
                              void* d_out, int out_size, void* d_ws, size_t ws_size,
                              hipStream_t stream) {
  const float* x         = (const float*)d_in[0];
  const int*   src       = (const int*)d_in[1];
  const int*   dst       = (const int*)d_in[2];
  const float* W_gat     = (const float*)d_in[3];
  const float* attn_l    = (const float*)d_in[4];
  const float* attn_r    = (const float*)d_in[5];
  const float* gate_m_W  = (const float*)d_in[6];
  const float* gate_m_b  = (const float*)d_in[7];
  const float* gate_fn_W = (const float*)d_in[8];
  const float* gate_fn_b = (const float*)d_in[9];
  const float* merge_W   = (const float*)d_in[10];
  const float* merge_b   = (const float*)d_in[11];
  float* out = (float*)d_out;

  char* ws = (char*)d_ws;
  size_t off = 0;
  auto alloc = [&](size_t bytes) -> void* {
    off = (off + 255) & ~(size_t)255;
    void* p = ws + off;
    off += bytes;
    return p;
  };
  int* cursor    = (int*)alloc((size_t)NN * 4);
  unsigned short* csr_src = (unsigned short*)alloc((size_t)NN * CAP * 2);
  float* epay = (float*)alloc((size_t)(NN + 1) * 8 * 4);   // {el,u} x 4 heads + sentinel
  float* er   = (float*)alloc((size_t)NN * 4 * 4);
  float* gx   = (float*)alloc((size_t)NN * 4 * 4);
  float* xm   = (float*)alloc((size_t)NN * 64 * 4);
  unsigned char* zq    = (unsigned char*)alloc((size_t)(NN + 1) * 64);
  unsigned char* featq = (unsigned char*)alloc((size_t)(NN + 1) * 256);
  unsigned short* xf     = (unsigned short*)alloc((size_t)(NRB + 4) * 512 * 8 * 2);
  unsigned short* Btf    = (unsigned short*)alloc((size_t)NBT * 8 * 2);
  unsigned short* mWf    = (unsigned short*)alloc((size_t)512 * 8 * 2);

  k_prep<<<PACK_BLKS + BT_BLKS + INIT_BLKS, 256, 0, stream>>>(
      x, W_gat, gate_m_W, merge_W, gate_fn_W, xf, Btf, mWf, cursor, zq, epay, featq);
  k_scatter<<<(NE + 255) / 256, 256, 0, stream>>>(src, dst, cursor, csr_src);
  k_gemm_mfma<<<(NN + 63) / 64, 256, 0, stream>>>(xf, Btf, gate_m_b, attn_l, attn_r,
                                                  featq, zq, xm, gx, epay, er);
  k_node<<<NN / 16, 256, 0, stream>>>(zq, featq, epay, er, gx, cursor, csr_src,
                                      gate_fn_W, gate_fn_b, mWf, xm, merge_b, out);
}

// Round 2
// 245.502 us; speedup vs baseline: 1.0519x; 1.0519x over previous
//
#include <hip/hip_runtime.h>
#include <math.h>

#define NN 50000
#define NE 800000
// IN=256, MAP=64, H=4, O=64
#define LEAKY 0.2f
#define NT 26              // 26 column tiles of 16 (416 cols, 400 real)
#define CAP 96             // padded CSR slots/node (max deg over Poisson(16) << 96)
#define NBT (8 * NT * 64)  // Btf fragment count
#define NRB 3125           // row blocks of 16 (NN/16 exact)
#define PACK_BLKS 6250     // NRB*512/256
#define BT_BLKS 54         // ceil((NBT+512)/256)
#define INIT_BLKS 196      // ceil(NN/256)

typedef short bf16x8 __attribute__((ext_vector_type(8)));
typedef float f32x4 __attribute__((ext_vector_type(4)));
typedef float f32x2 __attribute__((ext_vector_type(2)));

__device__ __forceinline__ unsigned short f2bf(float f) {
  unsigned u = __float_as_uint(f);
  u += 0x7fffu + ((u >> 16) & 1u);
  return (unsigned short)(u >> 16);
}
__device__ __forceinline__ float leaky(float v) { return v > 0.0f ? v : LEAKY * v; }
__device__ __forceinline__ float rlf(float v, int l) {
  return __uint_as_float(__builtin_amdgcn_readlane(__float_as_uint(v), l));
}
__device__ __forceinline__ int rli(int v, int l) {
  return __builtin_amdgcn_readlane(v, l);
}

// ---- fp8 e4m3fn helpers (HW cvt on gfx950; software fallback) ----
#if defined(__has_builtin)
#if __has_builtin(__builtin_amdgcn_cvt_pk_f32_fp8) && \
    __has_builtin(__builtin_amdgcn_cvt_pk_fp8_f32) && \
    __has_builtin(__builtin_amdgcn_cvt_f32_fp8)
#define FP8_HW 1
#endif
#endif

#ifdef FP8_HW
__device__ __forceinline__ unsigned char f2fp8(float v) {
  return (unsigned char)(__builtin_amdgcn_cvt_pk_fp8_f32(v, v, 0u, false) & 0xFF);
}
__device__ __forceinline__ f32x2 fp8x2_lo(unsigned int v) {
  return __builtin_amdgcn_cvt_pk_f32_fp8(v, false);   // word-select must be literal
}
__device__ __forceinline__ f32x2 fp8x2_hi(unsigned int v) {
  return __builtin_amdgcn_cvt_pk_f32_fp8(v, true);
}
__device__ __forceinline__ float fp8one(unsigned int v) {
  return __builtin_amdgcn_cvt_f32_fp8(v, 0);
}
#else
__device__ __forceinline__ unsigned char f2fp8(float f) {
  unsigned u = __float_as_uint(f);
  unsigned s = (u >> 31) << 7;
  unsigned a = u & 0x7FFFFFFFu;
  if (a >= 0x43E00000u) return (unsigned char)(s | 0x7E);
  if (a < 0x3C800000u) {
    float m = __uint_as_float(a) * 512.0f;
    int q = (int)(m + 0.5f); if (q > 7) q = 7;
    return (unsigned char)(s | q);
  }
  a += 0x7FFFFu + ((a >> 20) & 1);
  unsigned e = ((a >> 23) & 0xFF) - 120;
  if (e > 15) return (unsigned char)(s | 0x7E);
  return (unsigned char)(s | (e << 3) | ((a >> 20) & 7));
}
__device__ __forceinline__ float fp8dec1(unsigned b) {
  unsigned s = (b & 0x80u) << 24;
  unsigned em = b & 0x7Fu;
  unsigned e4 = em >> 3, m3 = em & 7;
  float v = e4 ? __uint_as_float(((e4 + 120) << 23) | (m3 << 20))
               : (float)m3 * 0.001953125f;
  return __uint_as_float(__float_as_uint(v) ^ s);
}
__device__ __forceinline__ f32x2 fp8x2_lo(unsigned int v) {
  f32x2 r; r[0] = fp8dec1(v & 0xFF); r[1] = fp8dec1((v >> 8) & 0xFF); return r;
}
__device__ __forceinline__ f32x2 fp8x2_hi(unsigned int v) {
  f32x2 r; r[0] = fp8dec1((v >> 16) & 0xFF); r[1] = fp8dec1((v >> 24) & 0xFF); return r;
}
__device__ __forceinline__ float fp8one(unsigned int v) { return fp8dec1(v & 0xFF); }
#endif

// Panel columns (416 = 26 tiles of 16):
//  c in 0..255   : feat, PERMUTED: panel col c holds W_gat column (c&3)*64 + (c>>2)
//                  so the GEMM output is featq[row][o*4+h] (o=c>>2, h=c&3)
//  c in 256..319 : gate_m_W (z)
//  c in 320..383 : merge_W[0:256] (xm)
//  c in 384..387 : gate_fn_W x-part (gx)
//  c in 388..391 : gate_fn_W mean-part (u)
//  c >= 392      : zero pad
__device__ __forceinline__ float panel_w(int col, int k,
    const float* W_gat, const float* gate_m_W, const float* merge_W,
    const float* gate_fn_W) {
  if (col < 256)      return W_gat[k * 256 + (col & 3) * 64 + (col >> 2)];
  else if (col < 320) return gate_m_W[k * 64 + (col - 256)];
  else if (col < 384) return merge_W[k * 64 + (col - 320)];
  else if (col < 388) return gate_fn_W[k * 4 + (col - 384)];
  else if (col < 392) return gate_fn_W[(320 + k) * 4 + (col - 388)];
  return 0.0f;
}

// Fused prep: x->xf (bf16 A-fragments) | Btf+mWf weight fragments | cursor zero + sentinels
__global__ __launch_bounds__(256) void k_prep(
    const float* __restrict__ x, const float* __restrict__ W_gat,
    const float* __restrict__ gate_m_W, const float* __restrict__ merge_W,
    const float* __restrict__ gate_fn_W,
    unsigned short* __restrict__ xf, unsigned short* __restrict__ Btf,
    unsigned short* __restrict__ mWf,
    int* __restrict__ cursor, unsigned char* __restrict__ zq,
    float* __restrict__ epay, unsigned char* __restrict__ featq) {
  int b = blockIdx.x, tid = threadIdx.x;
  if (b < PACK_BLKS) {
    // xf[((rowblk*8 + kq)*64 + lane)*8 + i] = bf16(x[rowblk*16 + (lane&15)][kq*32+(lane>>4)*8+i])
    int gid = b * 256 + tid;
    int rowblk = gid >> 9;
    int rem = gid & 511;
    int kq = rem >> 6, lane = rem & 63;
    int m = lane & 15, kg = lane >> 4;
    const float* p = x + (size_t)(rowblk * 16 + m) * 256 + kq * 32 + kg * 8;
    float4 fa = *(const float4*)p;
    float4 fb = *(const float4*)(p + 4);
    ushort4 o0, o1;
    o0.x = f2bf(fa.x); o0.y = f2bf(fa.y); o0.z = f2bf(fa.z); o0.w = f2bf(fa.w);
    o1.x = f2bf(fb.x); o1.y = f2bf(fb.y); o1.z = f2bf(fb.z); o1.w = f2bf(fb.w);
    ushort4* dst = (ushort4*)(xf + (size_t)gid * 8);
    dst[0] = o0; dst[1] = o1;
  } else if (b < PACK_BLKS + BT_BLKS) {
    int idx = (b - PACK_BLKS) * 256 + tid;
    if (idx < NBT) {
      int kq = idx / (NT * 64);
      int rem = idx - kq * (NT * 64);
      int t = rem >> 6, lane = rem & 63;
      int col = t * 16 + (lane & 15);
      int k = kq * 32 + (lane >> 4) * 8;
      unsigned short* o = Btf + (size_t)idx * 8;
#pragma unroll
      for (int i = 0; i < 8; ++i)
        o[i] = f2bf(panel_w(col, k + i, W_gat, gate_m_W, merge_W, gate_fn_W));
    } else if (idx < NBT + 512) {
      int idx2 = idx - NBT;
      int kq = idx2 >> 8;
      int rem = idx2 & 255;
      int t = rem >> 6, lane = rem & 63;
      int col = t * 16 + (lane & 15);
      int k = kq * 32 + ((lane >> 4) & 3) * 8;
      unsigned short* o = mWf + (size_t)idx2 * 8;
#pragma unroll
      for (int i = 0; i < 8; ++i)
        o[i] = f2bf(merge_W[(size_t)(256 + k + i) * 64 + col]);
    }
  } else {
    int i = (b - PACK_BLKS - BT_BLKS) * 256 + tid;
    if (i < NN) cursor[i] = 0;
    if (b == PACK_BLKS + BT_BLKS) {
      if (tid < 64) zq[(size_t)NN * 64 + tid] = 0xFE;   // sentinel z = -448
      if (tid < 8) epay[(size_t)NN * 8 + tid] = 0.0f;   // sentinel el/u = 0
      featq[(size_t)NN * 256 + tid] = 0;                // sentinel feat = 0 (no fp8 NaN)
    }
  }
}

// Padded CSR scatter (uint16 src ids: NN < 65536)
__global__ void k_scatter(const int* __restrict__ src, const int* __restrict__ dst,
                          int* __restrict__ cursor, unsigned short* __restrict__ csr_src) {
  int e = blockIdx.x * 256 + threadIdx.x;
  if (e < NE) {
    int n = dst[e];
    int pos = atomicAdd(&cursor[n], 1);
    if (pos < CAP) csr_src[n * CAP + pos] = (unsigned short)src[e];
  }
}

// bf16 MFMA GEMM: block = 64 rows x 416 cols, 4 waves; wave (rowHalf, colHalf) does
// TWO 16-row groups x 13 tiles (B loaded once per 32 rows -> half the B refetch).
// Ping-pong double-buffer on A and B fragments (vmcnt never drains the prefetch).
__global__ __launch_bounds__(256, 2) void k_gemm_mfma(
    const unsigned short* __restrict__ xf, const unsigned short* __restrict__ Btf,
    const float* __restrict__ gate_m_b,
    const float* __restrict__ attn_l, const float* __restrict__ attn_r,
    unsigned char* __restrict__ featq, unsigned char* __restrict__ zq,
    float* __restrict__ xm, float* __restrict__ gx, float* __restrict__ epay,
    float* __restrict__ erv) {
  __shared__ float els[64][4][2];
  __shared__ float ers[64][4][2];
  int lane = threadIdx.x & 63;
  int wave = threadIdx.x >> 6;
  int rowHalf = wave >> 1, colHalf = wave & 1;
  int rowB = blockIdx.x * 64;
  int row0 = rowB + rowHalf * 32;
  int t0 = colHalf * 13;
  int m = lane & 15, kg = lane >> 4;
  f32x4 zero = {0.f, 0.f, 0.f, 0.f};
  f32x4 acc[2][13];
#pragma unroll
  for (int g = 0; g < 2; ++g)
#pragma unroll
    for (int t = 0; t < 13; ++t) acc[g][t] = zero;

  const unsigned short* aB0 = xf + ((size_t)((blockIdx.x * 4 + rowHalf * 2) * 8) * 64 + lane) * 8;
  const unsigned short* aB1 = aB0 + (size_t)8 * 64 * 8;   // next 16-row block
  const unsigned short* bB = Btf + (size_t)(t0 * 64 + lane) * 8;

  bf16x8 aC0, aC1, aN0, aN1, bC[13], bN[13];
  aC0 = *(const bf16x8*)(aB0);
  aC1 = *(const bf16x8*)(aB1);
#pragma unroll
  for (int t = 0; t < 13; ++t)
    bC[t] = *(const bf16x8*)(bB + (size_t)t * 512);
#pragma unroll 1
  for (int kq = 0; kq < 8; kq += 2) {
    aN0 = *(const bf16x8*)(aB0 + (size_t)(kq + 1) * 512);
    aN1 = *(const bf16x8*)(aB1 + (size_t)(kq + 1) * 512);
#pragma unroll
    for (int t = 0; t < 13; ++t)
      bN[t] = *(const bf16x8*)(bB + ((size_t)(kq + 1) * NT + t) * 512);
#pragma unroll
    for (int t = 0; t < 13; ++t)
      acc[0][t] = __builtin_amdgcn_mfma_f32_16x16x32_bf16(aC0, bC[t], acc[0][t], 0, 0, 0);
#pragma unroll
    for (int t = 0; t < 13; ++t)
      acc[1][t] = __builtin_amdgcn_mfma_f32_16x16x32_bf16(aC1, bC[t], acc[1][t], 0, 0, 0);
    int kq2 = kq + 2 < 8 ? kq + 2 : 7;
    aC0 = *(const bf16x8*)(aB0 + (size_t)kq2 * 512);
    aC1 = *(const bf16x8*)(aB1 + (size_t)kq2 * 512);
#pragma unroll
    for (int t = 0; t < 13; ++t)
      bC[t] = *(const bf16x8*)(bB + ((size_t)kq2 * NT + t) * 512);
#pragma unroll
    for (int t = 0; t < 13; ++t)
      acc[0][t] = __builtin_amdgcn_mfma_f32_16x16x32_bf16(aN0, bN[t], acc[0][t], 0, 0, 0);
#pragma unroll
    for (int t = 0; t < 13; ++t)
      acc[1][t] = __builtin_amdgcn_mfma_f32_16x16x32_bf16(aN1, bN[t], acc[1][t], 0, 0, 0);
  }

  // fused el/er partials: h = m&3, o = (t0+t)*4 + (m>>2), feat tiles only
  int h = m & 3, od = m >> 2;
  float elp[2][4] = {{0,0,0,0},{0,0,0,0}}, erp[2][4] = {{0,0,0,0},{0,0,0,0}};
#pragma unroll
  for (int t = 0; t < 13; ++t) {
    if ((t0 + t) * 16 < 256) {
      int o = (t0 + t) * 4 + od;
      float al = attn_l[h * 64 + o];
      float ar = attn_r[h * 64 + o];
#pragma unroll
      for (int g = 0; g < 2; ++g)
#pragma unroll
        for (int r = 0; r < 4; ++r) {
          elp[g][r] += acc[g][t][r] * al;
          erp[g][r] += acc[g][t][r] * ar;
        }
    }
  }
#pragma unroll
  for (int g = 0; g < 2; ++g)
#pragma unroll
    for (int r = 0; r < 4; ++r) {
      elp[g][r] += __shfl_xor(elp[g][r], 4, 64); elp[g][r] += __shfl_xor(elp[g][r], 8, 64);
      erp[g][r] += __shfl_xor(erp[g][r], 4, 64); erp[g][r] += __shfl_xor(erp[g][r], 8, 64);
    }
  if (m < 4) {
#pragma unroll
    for (int g = 0; g < 2; ++g)
#pragma unroll
      for (int r = 0; r < 4; ++r) {
        els[rowHalf * 32 + g * 16 + kg * 4 + r][m][colHalf] = elp[g][r];
        ers[rowHalf * 32 + g * 16 + kg * 4 + r][m][colHalf] = erp[g][r];
      }
  }

  // epilogue stores: wave-uniform colHalf branch
#pragma unroll
  for (int g = 0; g < 2; ++g) {
    if (colHalf == 0) {
#pragma unroll
      for (int r = 0; r < 4; ++r) {
        int row = row0 + g * 16 + kg * 4 + r;
        if (row >= NN) continue;
#pragma unroll
        for (int t = 0; t < 13; ++t)
          featq[(size_t)row * 256 + t * 16 + m] = f2fp8(acc[g][t][r]);
      }
    } else {
#pragma unroll
      for (int r = 0; r < 4; ++r) {
        int row = row0 + g * 16 + kg * 4 + r;
        if (row >= NN) continue;
#pragma unroll
        for (int t = 0; t < 3; ++t)          // tiles 13..15: feat cols 208+
          featq[(size_t)row * 256 + 208 + t * 16 + m] = f2fp8(acc[g][t][r]);
#pragma unroll
        for (int t = 3; t < 7; ++t) {        // tiles 16..19: z
          int cc = (t - 3) * 16 + m;
          zq[(size_t)row * 64 + cc] = f2fp8(acc[g][t][r] + gate_m_b[cc]);
        }
#pragma unroll
        for (int t = 7; t < 11; ++t)         // tiles 20..23: xm
          xm[(size_t)row * 64 + (t - 7) * 16 + m] = acc[g][t][r];
        if (m < 4) gx[(size_t)row * 4 + m] = acc[g][11][r];                   // gx
        else if (m < 8) epay[(size_t)row * 8 + (m - 4) * 2 + 1] = acc[g][11][r];  // u
      }
    }
  }
  __syncthreads();
  int tid = threadIdx.x;
  {
    int rr = tid >> 2, h2 = tid & 3;
    int row = rowB + rr;
    if (row < NN) {
      epay[(size_t)row * 8 + h2 * 2] = els[rr][h2][0] + els[rr][h2][1];
      erv[(size_t)row * 4 + h2] = ers[rr][h2][0] + ers[rr][h2][1];
    }
  }
}

// Block = 16 nodes (4 per wave, sequential), single pass per node, 16-edge chunks.
// Round-0 structure (uniform-row loads via readlane -> SGPR base) + explicit
// latency hiding: (a) all 16 featq dword loads then all 16 zq byte loads issued
// into registers BEFORE the decode loop (counted-vmcnt overlap, ~32 loads in
// flight), (b) next chunk's csr_src prefetched before this chunk's decode,
// (c) packed f32x2 accumulate (v_pk_fma_f32).
__global__ __launch_bounds__(256) void k_node(
    const unsigned char* __restrict__ zq, const unsigned char* __restrict__ featq,
    const float* __restrict__ epay, const float* __restrict__ er,
    const float* __restrict__ gx,
    const int* __restrict__ cursor, const unsigned short* __restrict__ csr_src,
    const float* __restrict__ gate_fn_W, const float* __restrict__ gate_fn_b,
    const unsigned short* __restrict__ mWf, const float* __restrict__ xm,
    const float* __restrict__ merge_b, float* __restrict__ out) {
  __shared__ float WzT[4][64];             // gate_fn_W max_z-part, transposed [h][c]
  __shared__ float pbuf[4][16][4];         // [wave][edge][head]
  __shared__ unsigned short gLDS[16][72];  // gated bf16, padded stride
  int tid = threadIdx.x;
  {
    int c = tid >> 2, h = tid & 3;
    WzT[h][c] = gate_fn_W[(256 + c) * 4 + h];
  }
  __syncthreads();

  int lane = tid & 63, wave = tid >> 6;
  int hh = lane >> 4, le = lane & 15;
  int nodeBase = blockIdx.x * 16 + wave * 4;
#pragma unroll 1
  for (int i = 0; i < 4; ++i) {
    int node = nodeBase + i;                    // 3125*16 == NN exactly
    int deg = cursor[node]; if (deg > CAP) deg = CAP;
    float gated = 0.0f;
    if (deg > 0) {
      int rs = node * CAP, re = rs + deg;
      float er_h = er[(size_t)node * 4 + hh];
      f32x2 A01 = {0.f, 0.f}, A23 = {0.f, 0.f};
      float psum = 0, usum = 0;
      float mz = -INFINITY;
      int jj = rs + le;
      int s_l = (jj < re) ? (int)csr_src[jj] : NN;   // NN = sentinel row
#pragma unroll 1
      for (int j0 = rs; j0 < re; j0 += 16) {
        // prefetch next chunk's source ids (independent -> issues early)
        int jn = j0 + 16 + le;
        int s_nx = (jn < re) ? (int)csr_src[jn] : NN;
        bool valid = (j0 + le) < re;
        float2 eu = *(const float2*)(epay + ((size_t)(unsigned)s_l << 3) + hh * 2);
        float p = valid ? __expf(leaky(eu.x + er_h)) : 0.0f;
        psum += p;
        usum += eu.y;                                // sentinel u == 0
        pbuf[wave][le][hh] = p;                      // wave-synchronous broadcast
        // batched gather: issue all loads, then decode (max MLP)
        unsigned int fvr[16];
        unsigned int zvr[16];
#pragma unroll
        for (int e2 = 0; e2 < 16; ++e2) {
          int s = rli(s_l, e2);                      // SGPR row id -> scalar base
          fvr[e2] = *(const unsigned int*)(featq + ((size_t)(unsigned)s << 8) + lane * 4);
        }
#pragma unroll
        for (int e2 = 0; e2 < 16; ++e2) {
          int s = rli(s_l, e2);
          zvr[e2] = zq[((size_t)(unsigned)s << 6) + lane];
        }
#pragma unroll
        for (int e2 = 0; e2 < 16; ++e2) {
          float4 pv = *(const float4*)pbuf[wave][e2];   // ds_read_b128, uniform addr
          f32x2 p01 = {pv.x, pv.y};
          f32x2 p23 = {pv.z, pv.w};
          A01 += p01 * fp8x2_lo(fvr[e2]);
          A23 += p23 * fp8x2_hi(fvr[e2]);
          mz = fmaxf(mz, fp8one(zvr[e2]));
        }
        s_l = s_nx;
      }
      // reduce p/u sums within each 16-lane head group
#pragma unroll
      for (int off = 1; off < 16; off <<= 1) {
        psum += __shfl_xor(psum, off, 64);
        usum += __shfl_xor(usum, off, 64);
      }
      float s0 = rlf(psum, 0),  s1 = rlf(psum, 16);
      float s2 = rlf(psum, 32), s3 = rlf(psum, 48);
      float su0 = rlf(usum, 0),  su1 = rlf(usum, 16);
      float su2 = rlf(usum, 32), su3 = rlf(usum, 48);

      // gate: sigmoid(gx + Wz·max_z + mean-part + b)
      float g[4];
#pragma unroll
      for (int h = 0; h < 4; ++h) {
        float t = mz * WzT[h][lane];
#pragma unroll
        for (int off = 32; off; off >>= 1) t += __shfl_xor(t, off, 64);
        g[h] = t;
      }
      float inv_deg = 1.0f / (float)deg;
      float4 gx4 = *(const float4*)(gx + (size_t)node * 4);
      float g0 = 1.0f / (1.0f + __expf(-(g[0] + gx4.x + su0 * inv_deg + gate_fn_b[0])));
      float g1 = 1.0f / (1.0f + __expf(-(g[1] + gx4.y + su1 * inv_deg + gate_fn_b[1])));
      float g2 = 1.0f / (1.0f + __expf(-(g[2] + gx4.z + su2 * inv_deg + gate_fn_b[2])));
      float g3 = 1.0f / (1.0f + __expf(-(g[3] + gx4.w + su3 * inv_deg + gate_fn_b[3])));
      gated = 0.25f * (g0 * A01[0] / s0 + g1 * A01[1] / s1 +
                       g2 * A23[0] / s2 + g3 * A23[1] / s3);
    }
    gLDS[wave * 4 + i][lane] = f2bf(gated);
  }
  __syncthreads();

  // fused merge: out[16 rows][64] = gated @ merge_W[256:] + xm + merge_b
  // wave w computes column tile w (cols w*16..+15); A shared from gLDS.
  int m = lane & 15, kg = lane >> 4;
  f32x4 acc = {0.f, 0.f, 0.f, 0.f};
#pragma unroll
  for (int kq = 0; kq < 2; ++kq) {
    bf16x8 a = *(const bf16x8*)(&gLDS[m][kq * 32 + kg * 8]);
    bf16x8 b = *(const bf16x8*)(mWf + (((size_t)kq * 4 + wave) * 64 + lane) * 8);
    acc = __builtin_amdgcn_mfma_f32_16x16x32_bf16(a, b, acc, 0, 0, 0);
  }
  int c = wave * 16 + m;
  float mb = merge_b[c];
#pragma unroll
  for (int r = 0; r < 4; ++r) {
    int row = blockIdx.x * 16 + kg * 4 + r;
    out[(size_t)row * 64 + c] = acc[r] + xm[(size_t)row * 64 + c] + mb;
  }
}

extern "C" void kernel_launch(void* const* d_in, const int* in_sizes, int n_in,
                              void* d_out, int out_size, void* d_ws, size_t ws_size,
                              hipStream_t stream) {
  const float* x         = (const float*)d_in[0];
  const int*   src       = (const int*)d_in[1];
  const int*   dst       = (const int*)d_in[2];
  const float* W_gat     = (const float*)d_in[3];
  const float* attn_l    = (const float*)d_in[4];
  const float* attn_r    = (const float*)d_in[5];
  const float* gate_m_W  = (const float*)d_in[6];
  const float* gate_m_b  = (const float*)d_in[7];
  const float* gate_fn_W = (const float*)d_in[8];
  const float* gate_fn_b = (const float*)d_in[9];
  const float* merge_W   = (const float*)d_in[10];
  const float* merge_b   = (const float*)d_in[11];
  float* out = (float*)d_out;

  char* ws = (char*)d_ws;
  size_t off = 0;
  auto alloc = [&](size_t bytes) -> void* {
    off = (off + 255) & ~(size_t)255;
    void* p = ws + off;
    off += bytes;
    return p;
  };
  int* cursor    = (int*)alloc((size_t)NN * 4);
  unsigned short* csr_src = (unsigned short*)alloc((size_t)NN * CAP * 2);
  float* epay = (float*)alloc((size_t)(NN + 1) * 8 * 4);   // {el,u} x 4 heads + sentinel
  float* er   = (float*)alloc((size_t)NN * 4 * 4);
  float* gx   = (float*)alloc((size_t)NN * 4 * 4);
  float* xm   = (float*)alloc((size_t)NN * 64 * 4);
  unsigned char* zq    = (unsigned char*)alloc((size_t)(NN + 1) * 64);
  unsigned char* featq = (unsigned char*)alloc((size_t)(NN + 1) * 256);
  unsigned short* xf     = (unsigned short*)alloc((size_t)(NRB + 4) * 512 * 8 * 2);
  unsigned short* Btf    = (unsigned short*)alloc((size_t)NBT * 8 * 2);
  unsigned short* mWf    = (unsigned short*)alloc((size_t)512 * 8 * 2);

  k_prep<<<PACK_BLKS + BT_BLKS + INIT_BLKS, 256, 0, stream>>>(
      x, W_gat, gate_m_W, merge_W, gate_fn_W, xf, Btf, mWf, cursor, zq, epay, featq);
  k_scatter<<<(NE + 255) / 256, 256, 0, stream>>>(src, dst, cursor, csr_src);
  k_gemm_mfma<<<(NN + 63) / 64, 256, 0, stream>>>(xf, Btf, gate_m_b, attn_l, attn_r,
                                                  featq, zq, xm, gx, epay, er);
  k_node<<<NN / 16, 256, 0, stream>>>(zq, featq, epay, er, gx, cursor, csr_src,
                                      gate_fn_W, gate_fn_b, mWf, xm, merge_b, out);
}